// Round 4
// baseline (269.101 us; speedup 1.0000x reference)
//
#include <hip/hip_runtime.h>
#include <math.h>

// Problem constants (match reference setup_inputs)
constexpr int B = 16, H = 512, W = 512;
constexpr int NPIX = B * H * W;           // 4,194,304
constexpr int BLK = 256;
constexpr int PPT = 4;                    // pixels per thread (edt kernel)
constexpr int NBLK2 = NPIX / (BLK * PPT); // 4096

#define ALPHA_C 0.5
#define BETA_C 0.5
#define SMOOTH_C 1e-06
#define BIGV 1000000.0f

// ---------------------------------------------------------------------------
// Phase 1: per-row 1D distances via wave-parallel max/min scans.
// One wave per row; each lane owns 8 contiguous pixels. Outputs ONE
// interleaved field: u32 = (g_to_nearest_0 << 16) | g_to_nearest_1.
// Real distances <= 511 (exact in u16); rows missing a class clamp to
// 65535, whose square is a huge sentinel (cannot win vs any real candidate).
// Block 0 / thread 0 also zero-initializes the loss accumulators (this
// kernel fully precedes edt_loss in stream order).
// ---------------------------------------------------------------------------
__global__ void __launch_bounds__(256)
rowdist_kernel(const int* __restrict__ tgt,
               unsigned int* __restrict__ field,
               double* __restrict__ acc,
               unsigned int* __restrict__ cnt) {
    if (blockIdx.x == 0 && threadIdx.x == 0) {
        acc[0] = 0.0; acc[1] = 0.0; acc[2] = 0.0; acc[3] = 0.0;
        *cnt = 0u;
    }

    const int lane = threadIdx.x & 63;
    const int row  = blockIdx.x * 4 + (threadIdx.x >> 6);   // 4 waves/block
    const size_t base = (size_t)row * W + (size_t)lane * 8;

    const int4 t0 = *reinterpret_cast<const int4*>(tgt + base);
    const int4 t1 = *reinterpret_cast<const int4*>(tgt + base + 4);
    bool m[8] = { t0.x > 0, t0.y > 0, t0.z > 0, t0.w > 0,
                  t1.x > 0, t1.y > 0, t1.z > 0, t1.w > 0 };

    const float NEG = -(BIGV + 1.0f);      // identity: no hit yet (fwd)
    const float POS = (float)W + BIGV;     // identity: no hit ahead (bwd)
    const float wbase = (float)(lane * 8);

    // ---- lane-local last/first hit indices ----
    float la = NEG, lb = NEG;   // last 1 / 0 index within chunk
    float ra = POS, rb = POS;   // first 1 / 0 index within chunk
    #pragma unroll
    for (int j = 0; j < 8; ++j) {
        float w = wbase + (float)j;
        if (m[j]) la = w; else lb = w;
    }
    #pragma unroll
    for (int j = 7; j >= 0; --j) {
        float w = wbase + (float)j;
        if (m[j]) ra = w; else rb = w;
    }

    // ---- wave inclusive max-scan (prefix) ----
    float sa = la, sb = lb;
    #pragma unroll
    for (int off = 1; off < 64; off <<= 1) {
        float ua = __shfl_up(sa, off, 64);
        float ub = __shfl_up(sb, off, 64);
        if (lane >= off) { sa = fmaxf(sa, ua); sb = fmaxf(sb, ub); }
    }
    float carry_a = __shfl_up(sa, 1, 64); if (lane == 0) carry_a = NEG;
    float carry_b = __shfl_up(sb, 1, 64); if (lane == 0) carry_b = NEG;

    // ---- wave inclusive min-scan (suffix) ----
    float ta = ra, tb = rb;
    #pragma unroll
    for (int off = 1; off < 64; off <<= 1) {
        float ua = __shfl_down(ta, off, 64);
        float ub = __shfl_down(tb, off, 64);
        if (lane < 64 - off) { ta = fminf(ta, ua); tb = fminf(tb, ub); }
    }
    float rcarry_a = __shfl_down(ta, 1, 64); if (lane == 63) rcarry_a = POS;
    float rcarry_b = __shfl_down(tb, 1, 64); if (lane == 63) rcarry_b = POS;

    // ---- per-element distances ----
    float ga[8], gb[8];
    la = carry_a; lb = carry_b;
    #pragma unroll
    for (int j = 0; j < 8; ++j) {
        float w = wbase + (float)j;
        if (m[j]) la = w; else lb = w;
        ga[j] = w - la;
        gb[j] = w - lb;
    }
    ra = rcarry_a; rb = rcarry_b;
    #pragma unroll
    for (int j = 7; j >= 0; --j) {
        float w = wbase + (float)j;
        if (m[j]) ra = w; else rb = w;
        ga[j] = fminf(ga[j], ra - w);
        gb[j] = fminf(gb[j], rb - w);
    }

    // ---- pack (g1 | g0<<16), clamp to u16 ----
    unsigned int pk[8];
    #pragma unroll
    for (int j = 0; j < 8; ++j) {
        unsigned int ua = (unsigned int)fminf(ga[j], 65535.0f);
        unsigned int ub = (unsigned int)fminf(gb[j], 65535.0f);
        pk[j] = ua | (ub << 16);
    }
    uint4 o0 = make_uint4(pk[0], pk[1], pk[2], pk[3]);
    uint4 o1 = make_uint4(pk[4], pk[5], pk[6], pk[7]);
    *reinterpret_cast<uint4*>(field + base)     = o0;
    *reinterpret_cast<uint4*>(field + base + 4) = o1;
}

// ---------------------------------------------------------------------------
__device__ inline double wave_reduce(double v) {
    #pragma unroll
    for (int off = 32; off > 0; off >>= 1)
        v += __shfl_down(v, off, 64);
    return v;
}

// ---------------------------------------------------------------------------
// Phase 2: per pixel, dist = sqrt(min_{i'} (i-i')^2 + g_opp[i']^2) of the
// OPPOSITE class only (own-class EDT is 0 at the pixel; class inferred
// from ga==0). Window r=0..3 via uint4 loads (both fields, 4 pixels, one
// load per row-offset), rare tail loop beyond. Exact integer f32 math.
// Last finishing block computes the final scalar loss.
// ---------------------------------------------------------------------------
__global__ void __launch_bounds__(BLK)
edt_loss_kernel(const float* __restrict__ logits,
                const unsigned int* __restrict__ field,
                double* __restrict__ acc,
                unsigned int* __restrict__ cnt,
                float* __restrict__ out) {
    const int tid  = blockIdx.x * BLK + threadIdx.x;
    const int pix0 = tid * PPT;                 // 4 consecutive pixels, same row
    const int w0 = pix0 & (W - 1);
    const int i  = (pix0 >> 9) & (H - 1);       // W = 2^9
    const int b  = pix0 >> 18;                  // H*W = 2^18
    const unsigned int* img = field + (size_t)b * (H * W);

    const float4 lg = *reinterpret_cast<const float4*>(logits + pix0);

    // r = 0: class + initial best
    const uint4 v0 = *reinterpret_cast<const uint4*>(img + (size_t)i * W + w0);
    const unsigned int va[4] = { v0.x, v0.y, v0.z, v0.w };
    float best[4], tf[4];
    int shf[4];
    #pragma unroll
    for (int k = 0; k < 4; ++k) {
        unsigned int g1 = va[k] & 0xffffu;      // dist to nearest 1
        bool t = (g1 == 0u);                    // pixel class
        shf[k] = t ? 16 : 0;                    // opposite-field shift
        tf[k] = t ? 1.0f : 0.0f;
        float g0 = (float)((va[k] >> shf[k]) & 0xffffu);
        best[k] = g0 * g0;
    }

    // window r = 1..3: one uint4 load per row-offset (both fields, 4 px)
    const uint4 SENT = make_uint4(~0u, ~0u, ~0u, ~0u);
    #pragma unroll
    for (int r = 1; r <= 3; ++r) {
        const float rr = (float)(r * r);
        const uint4 vu = (i - r >= 0) ? *reinterpret_cast<const uint4*>(img + (size_t)(i - r) * W + w0) : SENT;
        const uint4 vd = (i + r <  H) ? *reinterpret_cast<const uint4*>(img + (size_t)(i + r) * W + w0) : SENT;
        const unsigned int au[4] = { vu.x, vu.y, vu.z, vu.w };
        const unsigned int ad[4] = { vd.x, vd.y, vd.z, vd.w };
        #pragma unroll
        for (int k = 0; k < 4; ++k) {
            float gu = (float)((au[k] >> shf[k]) & 0xffffu);
            float gd = (float)((ad[k] >> shf[k]) & 0xffffu);
            best[k] = fminf(best[k], fmaf(gu, gu, rr));
            best[k] = fminf(best[k], fmaf(gd, gd, rr));
        }
    }

    // rare tail (P ~ 2^-27 per pixel): only if best still exceeds 4^2
    #pragma unroll
    for (int k = 0; k < 4; ++k) {
        if (best[k] > 16.0f) {
            const unsigned int* col = img + w0 + k;
            for (int r = 4; r < H; ++r) {
                const float rr = (float)(r * r);
                if (rr >= best[k]) break;
                const int iu = i - r, id = i + r;
                if (iu >= 0) {
                    float g = (float)((col[(size_t)iu * W] >> shf[k]) & 0xffffu);
                    best[k] = fminf(best[k], fmaf(g, g, rr));
                }
                if (id < H) {
                    float g = (float)((col[(size_t)id * W] >> shf[k]) & 0xffffu);
                    best[k] = fminf(best[k], fmaf(g, g, rr));
                }
            }
        }
    }

    const float xv[4] = { lg.x, lg.y, lg.z, lg.w };
    double v_pd = 0.0, v_p = 0.0, v_t = 0.0, v_pt = 0.0;
    #pragma unroll
    for (int k = 0; k < 4; ++k) {
        const float dist = sqrtf(best[k]);      // own-class term is exactly 0
        const float p = 1.0f / (1.0f + __expf(-xv[k]));
        v_pd += (double)(p * dist);
        v_p  += (double)p;
        v_t  += (double)tf[k];
        v_pt += (double)(p * tf[k]);
    }

    v_pd = wave_reduce(v_pd);
    v_p  = wave_reduce(v_p);
    v_t  = wave_reduce(v_t);
    v_pt = wave_reduce(v_pt);

    __shared__ double sh[4][4];
    const int wid = threadIdx.x >> 6, lane = threadIdx.x & 63;
    if (lane == 0) {
        sh[wid][0] = v_pd; sh[wid][1] = v_p; sh[wid][2] = v_t; sh[wid][3] = v_pt;
    }
    __syncthreads();
    if (threadIdx.x == 0) {
        atomicAdd(&acc[0], sh[0][0] + sh[1][0] + sh[2][0] + sh[3][0]);
        atomicAdd(&acc[1], sh[0][1] + sh[1][1] + sh[2][1] + sh[3][1]);
        atomicAdd(&acc[2], sh[0][2] + sh[1][2] + sh[2][2] + sh[3][2]);
        atomicAdd(&acc[3], sh[0][3] + sh[1][3] + sh[2][3] + sh[3][3]);
        __threadfence();
        unsigned int old = atomicAdd(cnt, 1u);
        if (old == (unsigned int)(NBLK2 - 1)) {
            __threadfence();
            double sum_pd = __hip_atomic_load(&acc[0], __ATOMIC_RELAXED, __HIP_MEMORY_SCOPE_AGENT);
            double sum_p  = __hip_atomic_load(&acc[1], __ATOMIC_RELAXED, __HIP_MEMORY_SCOPE_AGENT);
            double sum_t  = __hip_atomic_load(&acc[2], __ATOMIC_RELAXED, __HIP_MEMORY_SCOPE_AGENT);
            double sum_pt = __hip_atomic_load(&acc[3], __ATOMIC_RELAXED, __HIP_MEMORY_SCOPE_AGENT);

            double mean_pd = sum_pd / (double)NPIX;
            double loss_b = BETA_C * mean_pd;
            double dice = (2.0 * sum_pt + SMOOTH_C) / (sum_p + sum_t + SMOOTH_C);
            double loss_d = 1.0 - dice;
            out[0] = (float)(ALPHA_C * loss_d + BETA_C * loss_b);
        }
    }
}

// ---------------------------------------------------------------------------
extern "C" void kernel_launch(void* const* d_in, const int* in_sizes, int n_in,
                              void* d_out, int out_size, void* d_ws, size_t ws_size,
                              hipStream_t stream) {
    const float* logits = (const float*)d_in[0];   // [16,1,512,512] f32
    const int* tgt      = (const int*)d_in[1];     // [16,1,512,512] i32 (0/1)
    float* out = (float*)d_out;                    // scalar

    // Workspace layout:
    //   [0, 32)    : double acc[4]
    //   [32, 36)   : uint cnt
    //   [64, ...)  : u32 field[NPIX] (interleaved u16 distances)
    double* acc = (double*)d_ws;
    unsigned int* cnt = (unsigned int*)((char*)d_ws + 32);
    unsigned int* field = (unsigned int*)((char*)d_ws + 64);

    rowdist_kernel<<<B * H / 4, 256, 0, stream>>>(tgt, field, acc, cnt);
    edt_loss_kernel<<<NBLK2, BLK, 0, stream>>>(logits, field, acc, cnt, out);
}

// Round 5
// 45.990 us; speedup vs baseline: 5.8513x; 5.8513x over previous
//
#include <hip/hip_runtime.h>
#include <math.h>

// Problem constants (match reference setup_inputs)
constexpr int B = 16, H = 512, W = 512;
constexpr int NPIX = B * H * W;           // 4,194,304
constexpr int BLK = 256;
constexpr int PPT = 4;                    // pixels per thread (edt kernel)
constexpr int NBLK2 = NPIX / (BLK * PPT); // 4096

#define ALPHA_C 0.5
#define BETA_C 0.5
#define SMOOTH_C 1e-06
#define BIGV 1000000.0f

// ---------------------------------------------------------------------------
// Phase 1: per-row 1D distances via wave-parallel max/min scans.
// One wave per row; each lane owns 8 contiguous pixels. Outputs ONE
// interleaved field: u32 = (g_to_nearest_0 << 16) | g_to_nearest_1.
// Real distances <= 511 (exact in u16); rows missing a class clamp to
// 65535, whose square is a huge sentinel. Exact-integer f32 math.
// ---------------------------------------------------------------------------
__global__ void __launch_bounds__(256)
rowdist_kernel(const int* __restrict__ tgt,
               unsigned int* __restrict__ field) {
    const int lane = threadIdx.x & 63;
    const int row  = blockIdx.x * 4 + (threadIdx.x >> 6);   // 4 waves/block
    const size_t base = (size_t)row * W + (size_t)lane * 8;

    const int4 t0 = *reinterpret_cast<const int4*>(tgt + base);
    const int4 t1 = *reinterpret_cast<const int4*>(tgt + base + 4);
    bool m[8] = { t0.x > 0, t0.y > 0, t0.z > 0, t0.w > 0,
                  t1.x > 0, t1.y > 0, t1.z > 0, t1.w > 0 };

    const float NEG = -(BIGV + 1.0f);      // identity: no hit yet (fwd)
    const float POS = (float)W + BIGV;     // identity: no hit ahead (bwd)
    const float wbase = (float)(lane * 8);

    // ---- lane-local last/first hit indices ----
    float la = NEG, lb = NEG;   // last 1 / 0 index within chunk
    float ra = POS, rb = POS;   // first 1 / 0 index within chunk
    #pragma unroll
    for (int j = 0; j < 8; ++j) {
        float w = wbase + (float)j;
        if (m[j]) la = w; else lb = w;
    }
    #pragma unroll
    for (int j = 7; j >= 0; --j) {
        float w = wbase + (float)j;
        if (m[j]) ra = w; else rb = w;
    }

    // ---- wave inclusive max-scan (prefix) ----
    float sa = la, sb = lb;
    #pragma unroll
    for (int off = 1; off < 64; off <<= 1) {
        float ua = __shfl_up(sa, off, 64);
        float ub = __shfl_up(sb, off, 64);
        if (lane >= off) { sa = fmaxf(sa, ua); sb = fmaxf(sb, ub); }
    }
    float carry_a = __shfl_up(sa, 1, 64); if (lane == 0) carry_a = NEG;
    float carry_b = __shfl_up(sb, 1, 64); if (lane == 0) carry_b = NEG;

    // ---- wave inclusive min-scan (suffix) ----
    float ta = ra, tb = rb;
    #pragma unroll
    for (int off = 1; off < 64; off <<= 1) {
        float ua = __shfl_down(ta, off, 64);
        float ub = __shfl_down(tb, off, 64);
        if (lane < 64 - off) { ta = fminf(ta, ua); tb = fminf(tb, ub); }
    }
    float rcarry_a = __shfl_down(ta, 1, 64); if (lane == 63) rcarry_a = POS;
    float rcarry_b = __shfl_down(tb, 1, 64); if (lane == 63) rcarry_b = POS;

    // ---- per-element distances ----
    float ga[8], gb[8];
    la = carry_a; lb = carry_b;
    #pragma unroll
    for (int j = 0; j < 8; ++j) {
        float w = wbase + (float)j;
        if (m[j]) la = w; else lb = w;
        ga[j] = w - la;
        gb[j] = w - lb;
    }
    ra = rcarry_a; rb = rcarry_b;
    #pragma unroll
    for (int j = 7; j >= 0; --j) {
        float w = wbase + (float)j;
        if (m[j]) ra = w; else rb = w;
        ga[j] = fminf(ga[j], ra - w);
        gb[j] = fminf(gb[j], rb - w);
    }

    // ---- pack (g1 | g0<<16), clamp to u16 ----
    unsigned int pk[8];
    #pragma unroll
    for (int j = 0; j < 8; ++j) {
        unsigned int ua = (unsigned int)fminf(ga[j], 65535.0f);
        unsigned int ub = (unsigned int)fminf(gb[j], 65535.0f);
        pk[j] = ua | (ub << 16);
    }
    uint4 o0 = make_uint4(pk[0], pk[1], pk[2], pk[3]);
    uint4 o1 = make_uint4(pk[4], pk[5], pk[6], pk[7]);
    *reinterpret_cast<uint4*>(field + base)     = o0;
    *reinterpret_cast<uint4*>(field + base + 4) = o1;
}

// ---------------------------------------------------------------------------
__device__ inline double wave_reduce(double v) {
    #pragma unroll
    for (int off = 32; off > 0; off >>= 1)
        v += __shfl_down(v, off, 64);
    return v;
}

// ---------------------------------------------------------------------------
// Phase 2: per pixel, dist = sqrt(min_{i'} (i-i')^2 + g_opp[i']^2) of the
// OPPOSITE class only (own-class EDT is 0 at the pixel; class inferred
// from g1==0). Window r=0..3 via uint4 loads (both fields, 4 pixels, one
// load per row-offset), rare tail loop beyond. Exact integer f32 math.
// Per-block partials (NO global atomics — contended f64 atomicAdd cost
// 240us in round 4); finalize kernel reduces them.
// ---------------------------------------------------------------------------
__global__ void __launch_bounds__(BLK)
edt_loss_kernel(const float* __restrict__ logits,
                const unsigned int* __restrict__ field,
                double* __restrict__ partials) {
    const int tid  = blockIdx.x * BLK + threadIdx.x;
    const int pix0 = tid * PPT;                 // 4 consecutive pixels, same row
    const int w0 = pix0 & (W - 1);
    const int i  = (pix0 >> 9) & (H - 1);       // W = 2^9
    const int b  = pix0 >> 18;                  // H*W = 2^18
    const unsigned int* img = field + (size_t)b * (H * W);

    const float4 lg = *reinterpret_cast<const float4*>(logits + pix0);

    // r = 0: class + initial best
    const uint4 v0 = *reinterpret_cast<const uint4*>(img + (size_t)i * W + w0);
    const unsigned int va[4] = { v0.x, v0.y, v0.z, v0.w };
    float best[4], tf[4];
    int shf[4];
    #pragma unroll
    for (int k = 0; k < 4; ++k) {
        unsigned int g1 = va[k] & 0xffffu;      // dist to nearest 1
        bool t = (g1 == 0u);                    // pixel class
        shf[k] = t ? 16 : 0;                    // opposite-field shift
        tf[k] = t ? 1.0f : 0.0f;
        float g0 = (float)((va[k] >> shf[k]) & 0xffffu);
        best[k] = g0 * g0;
    }

    // window r = 1..3: one uint4 load per row-offset (both fields, 4 px)
    const uint4 SENT = make_uint4(~0u, ~0u, ~0u, ~0u);
    #pragma unroll
    for (int r = 1; r <= 3; ++r) {
        const float rr = (float)(r * r);
        const uint4 vu = (i - r >= 0) ? *reinterpret_cast<const uint4*>(img + (size_t)(i - r) * W + w0) : SENT;
        const uint4 vd = (i + r <  H) ? *reinterpret_cast<const uint4*>(img + (size_t)(i + r) * W + w0) : SENT;
        const unsigned int au[4] = { vu.x, vu.y, vu.z, vu.w };
        const unsigned int ad[4] = { vd.x, vd.y, vd.z, vd.w };
        #pragma unroll
        for (int k = 0; k < 4; ++k) {
            float gu = (float)((au[k] >> shf[k]) & 0xffffu);
            float gd = (float)((ad[k] >> shf[k]) & 0xffffu);
            best[k] = fminf(best[k], fmaf(gu, gu, rr));
            best[k] = fminf(best[k], fmaf(gd, gd, rr));
        }
    }

    // rare tail: only if best still exceeds 4^2
    #pragma unroll
    for (int k = 0; k < 4; ++k) {
        if (best[k] > 16.0f) {
            const unsigned int* col = img + w0 + k;
            for (int r = 4; r < H; ++r) {
                const float rr = (float)(r * r);
                if (rr >= best[k]) break;
                const int iu = i - r, id = i + r;
                if (iu >= 0) {
                    float g = (float)((col[(size_t)iu * W] >> shf[k]) & 0xffffu);
                    best[k] = fminf(best[k], fmaf(g, g, rr));
                }
                if (id < H) {
                    float g = (float)((col[(size_t)id * W] >> shf[k]) & 0xffffu);
                    best[k] = fminf(best[k], fmaf(g, g, rr));
                }
            }
        }
    }

    const float xv[4] = { lg.x, lg.y, lg.z, lg.w };
    double v_pd = 0.0, v_p = 0.0, v_t = 0.0, v_pt = 0.0;
    #pragma unroll
    for (int k = 0; k < 4; ++k) {
        const float dist = sqrtf(best[k]);      // own-class term is exactly 0
        const float p = 1.0f / (1.0f + __expf(-xv[k]));
        v_pd += (double)(p * dist);
        v_p  += (double)p;
        v_t  += (double)tf[k];
        v_pt += (double)(p * tf[k]);
    }

    v_pd = wave_reduce(v_pd);
    v_p  = wave_reduce(v_p);
    v_t  = wave_reduce(v_t);
    v_pt = wave_reduce(v_pt);

    __shared__ double sh[4][4];
    const int wid = threadIdx.x >> 6, lane = threadIdx.x & 63;
    if (lane == 0) {
        sh[wid][0] = v_pd; sh[wid][1] = v_p; sh[wid][2] = v_t; sh[wid][3] = v_pt;
    }
    __syncthreads();
    if (threadIdx.x == 0) {
        double* outp = partials + (size_t)blockIdx.x * 4;
        outp[0] = sh[0][0] + sh[1][0] + sh[2][0] + sh[3][0];
        outp[1] = sh[0][1] + sh[1][1] + sh[2][1] + sh[3][1];
        outp[2] = sh[0][2] + sh[1][2] + sh[2][2] + sh[3][2];
        outp[3] = sh[0][3] + sh[1][3] + sh[2][3] + sh[3][3];
    }
}

// ---------------------------------------------------------------------------
// Finalize: reduce NBLK2 partial quads, compute scalar loss.
// ---------------------------------------------------------------------------
__global__ void finalize_kernel(const double* __restrict__ partials,
                                float* __restrict__ out) {
    double a0 = 0.0, a1 = 0.0, a2 = 0.0, a3 = 0.0;
    for (int j = threadIdx.x; j < NBLK2; j += BLK) {
        const double* p = partials + (size_t)j * 4;
        a0 += p[0]; a1 += p[1]; a2 += p[2]; a3 += p[3];
    }
    a0 = wave_reduce(a0);
    a1 = wave_reduce(a1);
    a2 = wave_reduce(a2);
    a3 = wave_reduce(a3);

    __shared__ double sh[4][4];
    const int wid = threadIdx.x >> 6, lane = threadIdx.x & 63;
    if (lane == 0) {
        sh[wid][0] = a0; sh[wid][1] = a1; sh[wid][2] = a2; sh[wid][3] = a3;
    }
    __syncthreads();
    if (threadIdx.x == 0) {
        double sum_pd = sh[0][0] + sh[1][0] + sh[2][0] + sh[3][0];
        double sum_p  = sh[0][1] + sh[1][1] + sh[2][1] + sh[3][1];
        double sum_t  = sh[0][2] + sh[1][2] + sh[2][2] + sh[3][2];
        double sum_pt = sh[0][3] + sh[1][3] + sh[2][3] + sh[3][3];

        double mean_pd = sum_pd / (double)NPIX;
        double loss_b = BETA_C * mean_pd;
        double dice = (2.0 * sum_pt + SMOOTH_C) / (sum_p + sum_t + SMOOTH_C);
        double loss_d = 1.0 - dice;
        out[0] = (float)(ALPHA_C * loss_d + BETA_C * loss_b);
    }
}

// ---------------------------------------------------------------------------
extern "C" void kernel_launch(void* const* d_in, const int* in_sizes, int n_in,
                              void* d_out, int out_size, void* d_ws, size_t ws_size,
                              hipStream_t stream) {
    const float* logits = (const float*)d_in[0];   // [16,1,512,512] f32
    const int* tgt      = (const int*)d_in[1];     // [16,1,512,512] i32 (0/1)
    float* out = (float*)d_out;                    // scalar

    // Workspace layout:
    //   [0, 128KB)   : double partials[NBLK2][4]
    //   [128KB, ...) : u32 field[NPIX] (interleaved u16 distances)
    double* partials = (double*)d_ws;
    unsigned int* field = (unsigned int*)((char*)d_ws + (size_t)NBLK2 * 4 * sizeof(double));

    rowdist_kernel<<<B * H / 4, 256, 0, stream>>>(tgt, field);
    edt_loss_kernel<<<NBLK2, BLK, 0, stream>>>(logits, field, partials);
    finalize_kernel<<<1, BLK, 0, stream>>>(partials, out);
}

// Round 6
// 24.918 us; speedup vs baseline: 10.7996x; 1.8457x over previous
//
#include <hip/hip_runtime.h>
#include <math.h>

// Problem constants (match reference setup_inputs)
constexpr int B = 16, H = 512, W = 512;
constexpr int NPIX = B * H * W;          // 4,194,304
constexpr int ROWS = 8;                  // pixel rows per block
constexpr int HALO = 3;                  // in-LDS window radius
constexpr int LROWS = ROWS + 2 * HALO;   // 14 LDS rows
constexpr int TPB = 512;                 // 8 waves per block
constexpr int NBLK = B * (H / ROWS);     // 1024 blocks

#define ALPHA_C 0.5
#define BETA_C 0.5
#define SMOOTH_C 1e-06
#define BIGV 1000000.0f

__device__ inline double wave_reduce(double v) {
    #pragma unroll
    for (int off = 32; off > 0; off >>= 1)
        v += __shfl_down(v, off, 64);
    return v;
}

// Exact nearest-opposite-class distance within one row, scanning outward
// from column c. Used only by the (astronomically rare) tail path.
__device__ int row_nearest(const int* __restrict__ rowp, int c, bool oppOne) {
    for (int d = 0; d < W; ++d) {
        int l = c - d, r = c + d;
        if (l >= 0 && ((rowp[l] > 0) == oppOne)) return d;
        if (r <  W && ((rowp[r] > 0) == oppOne)) return d;
    }
    return 65535;
}

// ---------------------------------------------------------------------------
// Fused kernel. Each block owns an 8-row strip of one image.
// Phase A: the block's 8 waves compute exact 1D row distances (wave-parallel
//   max/min scans, bitwise-identical to the reference recurrence: all values
//   < 2^24, exact in f32) for rows r0-3 .. r0+10, packed u16x2 into LDS.
//   Out-of-image rows get the 0xFFFFFFFF sentinel (g=65535; g^2 can't win).
// Phase B: each wave handles one pixel row; each lane owns cols [lane*4,+4)
//   and [lane*4+256,+4) (16B/lane -> conflict-free LDS b128, coalesced
//   logits float4). dist = sqrt(min_{|r|<=3} g_opp^2 + r^2) with exact
//   early-exit tail fallback (recomputes far rows from tgt on demand).
//   Own-class EDT term is exactly 0 at the pixel; class = (g1==0).
// Per-block f64 partials; finalize kernel reduces 1024 quads.
// ---------------------------------------------------------------------------
__global__ void __launch_bounds__(TPB, 4)
edt_fused_kernel(const float* __restrict__ logits,
                 const int* __restrict__ tgt,
                 double* __restrict__ partials) {
    __shared__ __align__(16) unsigned int gf[LROWS][W];   // 28 KB
    __shared__ double sh[8][4];

    const int lane = threadIdx.x & 63;
    const int wv   = threadIdx.x >> 6;          // 0..7
    const int b    = blockIdx.x >> 6;           // image index
    const int r0   = (blockIdx.x & 63) * ROWS;  // first pixel row (image-local)
    const int* timg = tgt + (size_t)b * H * W;

    const float NEG = -(BIGV + 1.0f);
    const float POS = (float)W + BIGV;
    const float wbase = (float)(lane * 8);

    // ---------------- Phase A: row scans into LDS ----------------
    for (int s = wv; s < LROWS; s += 8) {
        const int grow = r0 - HALO + s;
        if (grow < 0 || grow >= H) {
            const uint4 sent = make_uint4(~0u, ~0u, ~0u, ~0u);
            *reinterpret_cast<uint4*>(&gf[s][lane * 8])     = sent;
            *reinterpret_cast<uint4*>(&gf[s][lane * 8 + 4]) = sent;
            continue;
        }
        const int* rowp = timg + (size_t)grow * W;
        const int4 t0 = *reinterpret_cast<const int4*>(rowp + lane * 8);
        const int4 t1 = *reinterpret_cast<const int4*>(rowp + lane * 8 + 4);
        bool m[8] = { t0.x > 0, t0.y > 0, t0.z > 0, t0.w > 0,
                      t1.x > 0, t1.y > 0, t1.z > 0, t1.w > 0 };

        // lane-local last/first hit indices
        float la = NEG, lb = NEG, ra = POS, rb = POS;
        #pragma unroll
        for (int j = 0; j < 8; ++j) {
            float w = wbase + (float)j;
            if (m[j]) la = w; else lb = w;
        }
        #pragma unroll
        for (int j = 7; j >= 0; --j) {
            float w = wbase + (float)j;
            if (m[j]) ra = w; else rb = w;
        }

        // wave inclusive max-scan (prefix)
        float sa = la, sb = lb;
        #pragma unroll
        for (int off = 1; off < 64; off <<= 1) {
            float ua = __shfl_up(sa, off, 64);
            float ub = __shfl_up(sb, off, 64);
            if (lane >= off) { sa = fmaxf(sa, ua); sb = fmaxf(sb, ub); }
        }
        float carry_a = __shfl_up(sa, 1, 64); if (lane == 0) carry_a = NEG;
        float carry_b = __shfl_up(sb, 1, 64); if (lane == 0) carry_b = NEG;

        // wave inclusive min-scan (suffix)
        float ta = ra, tb = rb;
        #pragma unroll
        for (int off = 1; off < 64; off <<= 1) {
            float ua = __shfl_down(ta, off, 64);
            float ub = __shfl_down(tb, off, 64);
            if (lane < 64 - off) { ta = fminf(ta, ua); tb = fminf(tb, ub); }
        }
        float rcarry_a = __shfl_down(ta, 1, 64); if (lane == 63) rcarry_a = POS;
        float rcarry_b = __shfl_down(tb, 1, 64); if (lane == 63) rcarry_b = POS;

        // per-element distances
        float ga[8], gb[8];
        la = carry_a; lb = carry_b;
        #pragma unroll
        for (int j = 0; j < 8; ++j) {
            float w = wbase + (float)j;
            if (m[j]) la = w; else lb = w;
            ga[j] = w - la;
            gb[j] = w - lb;
        }
        ra = rcarry_a; rb = rcarry_b;
        #pragma unroll
        for (int j = 7; j >= 0; --j) {
            float w = wbase + (float)j;
            if (m[j]) ra = w; else rb = w;
            ga[j] = fminf(ga[j], ra - w);
            gb[j] = fminf(gb[j], rb - w);
        }

        unsigned int pk[8];
        #pragma unroll
        for (int j = 0; j < 8; ++j) {
            unsigned int ua = (unsigned int)fminf(ga[j], 65535.0f);  // dist to 1
            unsigned int ub = (unsigned int)fminf(gb[j], 65535.0f);  // dist to 0
            pk[j] = ua | (ub << 16);
        }
        *reinterpret_cast<uint4*>(&gf[s][lane * 8])     = make_uint4(pk[0], pk[1], pk[2], pk[3]);
        *reinterpret_cast<uint4*>(&gf[s][lane * 8 + 4]) = make_uint4(pk[4], pk[5], pk[6], pk[7]);
    }
    __syncthreads();

    // ---------------- Phase B: window search + loss ----------------
    const int i  = r0 + wv;           // this wave's pixel row (image-local)
    const int ci = wv + HALO;         // its LDS row
    const int c0 = lane * 4;          // group A cols; group B at +256
    const size_t rowoff = (size_t)b * H * W + (size_t)i * W;

    const float4 lgA = *reinterpret_cast<const float4*>(logits + rowoff + c0);
    const float4 lgB = *reinterpret_cast<const float4*>(logits + rowoff + c0 + 256);
    const uint4  vA  = *reinterpret_cast<const uint4*>(&gf[ci][c0]);
    const uint4  vB  = *reinterpret_cast<const uint4*>(&gf[ci][c0 + 256]);

    const unsigned int va[8] = { vA.x, vA.y, vA.z, vA.w, vB.x, vB.y, vB.z, vB.w };
    const float xv[8] = { lgA.x, lgA.y, lgA.z, lgA.w, lgB.x, lgB.y, lgB.z, lgB.w };

    float best[8], tf[8];
    int shf[8];
    #pragma unroll
    for (int k = 0; k < 8; ++k) {
        bool t = ((va[k] & 0xffffu) == 0u);     // g1==0 <=> target==1
        shf[k] = t ? 16 : 0;                    // opposite-field shift
        tf[k] = t ? 1.0f : 0.0f;
        float g = (float)((va[k] >> shf[k]) & 0xffffu);
        best[k] = g * g;
    }

    #pragma unroll
    for (int r = 1; r <= 3; ++r) {
        const float rr = (float)(r * r);
        const uint4 uA = *reinterpret_cast<const uint4*>(&gf[ci - r][c0]);
        const uint4 uB = *reinterpret_cast<const uint4*>(&gf[ci - r][c0 + 256]);
        const uint4 dA = *reinterpret_cast<const uint4*>(&gf[ci + r][c0]);
        const uint4 dB = *reinterpret_cast<const uint4*>(&gf[ci + r][c0 + 256]);
        const unsigned int au[8] = { uA.x, uA.y, uA.z, uA.w, uB.x, uB.y, uB.z, uB.w };
        const unsigned int ad[8] = { dA.x, dA.y, dA.z, dA.w, dB.x, dB.y, dB.z, dB.w };
        #pragma unroll
        for (int k = 0; k < 8; ++k) {
            float gu = (float)((au[k] >> shf[k]) & 0xffffu);
            float gd = (float)((ad[k] >> shf[k]) & 0xffffu);
            best[k] = fminf(best[k], fmaf(gu, gu, rr));
            best[k] = fminf(best[k], fmaf(gd, gd, rr));
        }
    }

    // exact tail fallback (P ~ 2^-40 per pixel): recompute far rows on demand
    #pragma unroll
    for (int k = 0; k < 8; ++k) {
        if (best[k] > (float)(HALO + 1) * (HALO + 1)) {
            const int col = (k < 4) ? (c0 + k) : (c0 + 256 + k - 4);
            const bool oppOne = (tf[k] == 0.0f);   // opposite class
            for (int r = HALO + 1; r < H; ++r) {
                const float rr = (float)(r * r);
                if (rr >= best[k]) break;
                const int ju = i - r, jd = i + r;
                if (ju >= 0) {
                    float g = (float)row_nearest(timg + (size_t)ju * W, col, oppOne);
                    best[k] = fminf(best[k], fmaf(g, g, rr));
                }
                if (jd < H) {
                    float g = (float)row_nearest(timg + (size_t)jd * W, col, oppOne);
                    best[k] = fminf(best[k], fmaf(g, g, rr));
                }
            }
        }
    }

    double v_pd = 0.0, v_p = 0.0, v_t = 0.0, v_pt = 0.0;
    #pragma unroll
    for (int k = 0; k < 8; ++k) {
        const float dist = sqrtf(best[k]);      // own-class term is exactly 0
        const float p = 1.0f / (1.0f + __expf(-xv[k]));
        v_pd += (double)(p * dist);
        v_p  += (double)p;
        v_t  += (double)tf[k];
        v_pt += (double)(p * tf[k]);
    }

    v_pd = wave_reduce(v_pd);
    v_p  = wave_reduce(v_p);
    v_t  = wave_reduce(v_t);
    v_pt = wave_reduce(v_pt);

    if (lane == 0) {
        sh[wv][0] = v_pd; sh[wv][1] = v_p; sh[wv][2] = v_t; sh[wv][3] = v_pt;
    }
    __syncthreads();
    if (threadIdx.x == 0) {
        double s0 = 0.0, s1 = 0.0, s2 = 0.0, s3 = 0.0;
        #pragma unroll
        for (int q = 0; q < 8; ++q) {
            s0 += sh[q][0]; s1 += sh[q][1]; s2 += sh[q][2]; s3 += sh[q][3];
        }
        double* outp = partials + (size_t)blockIdx.x * 4;
        outp[0] = s0; outp[1] = s1; outp[2] = s2; outp[3] = s3;
    }
}

// ---------------------------------------------------------------------------
// Finalize: reduce NBLK partial quads, compute scalar loss.
// ---------------------------------------------------------------------------
__global__ void finalize_kernel(const double* __restrict__ partials,
                                float* __restrict__ out) {
    double a0 = 0.0, a1 = 0.0, a2 = 0.0, a3 = 0.0;
    for (int j = threadIdx.x; j < NBLK; j += 256) {
        const double* p = partials + (size_t)j * 4;
        a0 += p[0]; a1 += p[1]; a2 += p[2]; a3 += p[3];
    }
    a0 = wave_reduce(a0);
    a1 = wave_reduce(a1);
    a2 = wave_reduce(a2);
    a3 = wave_reduce(a3);

    __shared__ double sh[4][4];
    const int wid = threadIdx.x >> 6, lane = threadIdx.x & 63;
    if (lane == 0) {
        sh[wid][0] = a0; sh[wid][1] = a1; sh[wid][2] = a2; sh[wid][3] = a3;
    }
    __syncthreads();
    if (threadIdx.x == 0) {
        double sum_pd = sh[0][0] + sh[1][0] + sh[2][0] + sh[3][0];
        double sum_p  = sh[0][1] + sh[1][1] + sh[2][1] + sh[3][1];
        double sum_t  = sh[0][2] + sh[1][2] + sh[2][2] + sh[3][2];
        double sum_pt = sh[0][3] + sh[1][3] + sh[2][3] + sh[3][3];

        double mean_pd = sum_pd / (double)NPIX;
        double loss_b = BETA_C * mean_pd;
        double dice = (2.0 * sum_pt + SMOOTH_C) / (sum_p + sum_t + SMOOTH_C);
        double loss_d = 1.0 - dice;
        out[0] = (float)(ALPHA_C * loss_d + BETA_C * loss_b);
    }
}

// ---------------------------------------------------------------------------
extern "C" void kernel_launch(void* const* d_in, const int* in_sizes, int n_in,
                              void* d_out, int out_size, void* d_ws, size_t ws_size,
                              hipStream_t stream) {
    const float* logits = (const float*)d_in[0];   // [16,1,512,512] f32
    const int* tgt      = (const int*)d_in[1];     // [16,1,512,512] i32 (0/1)
    float* out = (float*)d_out;                    // scalar

    // Workspace: double partials[NBLK][4] (32 KB)
    double* partials = (double*)d_ws;

    edt_fused_kernel<<<NBLK, TPB, 0, stream>>>(logits, tgt, partials);
    finalize_kernel<<<1, 256, 0, stream>>>(partials, out);
}

// Round 7
// 22.349 us; speedup vs baseline: 12.0406x; 1.1149x over previous
//
#include <hip/hip_runtime.h>
#include <math.h>

// Problem constants (match reference setup_inputs)
constexpr int B = 16, H = 512, W = 512;
constexpr int NPIX = B * H * W;          // 4,194,304
constexpr int ROWS = 16;                 // pixel rows per block
constexpr int HALO = 3;                  // in-LDS window radius
constexpr int LROWS = ROWS + 2 * HALO;   // 22 LDS rows
constexpr int TPB = 512;                 // 8 waves per block
constexpr int NBLK = B * (H / ROWS);     // 512 blocks

#define ALPHA_C 0.5
#define BETA_C 0.5
#define SMOOTH_C 1e-06
#define BIGV 1000000.0f

__device__ inline float wave_reduce_f(float v) {
    #pragma unroll
    for (int off = 32; off > 0; off >>= 1)
        v += __shfl_down(v, off, 64);
    return v;
}

__device__ inline double wave_reduce_d(double v) {
    #pragma unroll
    for (int off = 32; off > 0; off >>= 1)
        v += __shfl_down(v, off, 64);
    return v;
}

// Exact nearest-opposite-class distance within one row, scanning outward
// from column c. Used only by the (astronomically rare) tail path.
__device__ int row_nearest(const int* __restrict__ rowp, int c, bool oppOne) {
    for (int d = 0; d < W; ++d) {
        int l = c - d, r = c + d;
        if (l >= 0 && ((rowp[l] > 0) == oppOne)) return d;
        if (r <  W && ((rowp[r] > 0) == oppOne)) return d;
    }
    return 65535;
}

// ---------------------------------------------------------------------------
// Fused kernel. Each block owns a 16-row strip of one image.
// Phase A: 8 waves compute exact 1D row distances (wave-parallel max/min
//   scans, bitwise-identical to the reference recurrence) for rows
//   r0-3 .. r0+18, packed u16x2 into LDS. Out-of-image rows get the
//   0xFFFFFFFF sentinel (g=65535; g^2+rr < 2^32, can never win).
// Phase B: each wave handles 2 pixel rows; each lane owns cols [lane*4,+4)
//   and [+256,+4) (16B/lane -> conflict-free LDS b128, coalesced float4).
//   Window candidates in u32 (v_mad_u32_u24: g*g+r^2, min_u32) — compares
//   identical to the reference's exact-integer f32 mins. Exact early-exit
//   tail fallback recomputes far rows from tgt on demand (f32, still exact:
//   real values < 2^24). Own-class EDT term is 0 at the pixel (class=g1==0).
// Per-block f64 partials; finalize kernel reduces 512 quads.
// ---------------------------------------------------------------------------
__global__ void __launch_bounds__(TPB, 4)
edt_fused_kernel(const float* __restrict__ logits,
                 const int* __restrict__ tgt,
                 double* __restrict__ partials) {
    __shared__ __align__(16) unsigned int gf[LROWS][W];   // 44 KB
    __shared__ double sh[8][4];

    const int lane = threadIdx.x & 63;
    const int wv   = threadIdx.x >> 6;          // 0..7
    const int b    = blockIdx.x >> 5;           // image index (32 strips/image)
    const int r0   = (blockIdx.x & 31) * ROWS;  // first pixel row (image-local)
    const int* timg = tgt + (size_t)b * H * W;

    const float NEG = -(BIGV + 1.0f);
    const float POS = (float)W + BIGV;
    const float wbase = (float)(lane * 8);

    // ---------------- Phase A: row scans into LDS ----------------
    for (int s = wv; s < LROWS; s += 8) {
        const int grow = r0 - HALO + s;
        if (grow < 0 || grow >= H) {
            const uint4 sent = make_uint4(~0u, ~0u, ~0u, ~0u);
            *reinterpret_cast<uint4*>(&gf[s][lane * 8])     = sent;
            *reinterpret_cast<uint4*>(&gf[s][lane * 8 + 4]) = sent;
            continue;
        }
        const int* rowp = timg + (size_t)grow * W;
        const int4 t0 = *reinterpret_cast<const int4*>(rowp + lane * 8);
        const int4 t1 = *reinterpret_cast<const int4*>(rowp + lane * 8 + 4);
        bool m[8] = { t0.x > 0, t0.y > 0, t0.z > 0, t0.w > 0,
                      t1.x > 0, t1.y > 0, t1.z > 0, t1.w > 0 };

        // lane-local last/first hit indices
        float la = NEG, lb = NEG, ra = POS, rb = POS;
        #pragma unroll
        for (int j = 0; j < 8; ++j) {
            float w = wbase + (float)j;
            if (m[j]) la = w; else lb = w;
        }
        #pragma unroll
        for (int j = 7; j >= 0; --j) {
            float w = wbase + (float)j;
            if (m[j]) ra = w; else rb = w;
        }

        // wave inclusive max-scan (prefix)
        float sa = la, sb = lb;
        #pragma unroll
        for (int off = 1; off < 64; off <<= 1) {
            float ua = __shfl_up(sa, off, 64);
            float ub = __shfl_up(sb, off, 64);
            if (lane >= off) { sa = fmaxf(sa, ua); sb = fmaxf(sb, ub); }
        }
        float carry_a = __shfl_up(sa, 1, 64); if (lane == 0) carry_a = NEG;
        float carry_b = __shfl_up(sb, 1, 64); if (lane == 0) carry_b = NEG;

        // wave inclusive min-scan (suffix)
        float ta = ra, tb = rb;
        #pragma unroll
        for (int off = 1; off < 64; off <<= 1) {
            float ua = __shfl_down(ta, off, 64);
            float ub = __shfl_down(tb, off, 64);
            if (lane < 64 - off) { ta = fminf(ta, ua); tb = fminf(tb, ub); }
        }
        float rcarry_a = __shfl_down(ta, 1, 64); if (lane == 63) rcarry_a = POS;
        float rcarry_b = __shfl_down(tb, 1, 64); if (lane == 63) rcarry_b = POS;

        // per-element distances
        float ga[8], gb[8];
        la = carry_a; lb = carry_b;
        #pragma unroll
        for (int j = 0; j < 8; ++j) {
            float w = wbase + (float)j;
            if (m[j]) la = w; else lb = w;
            ga[j] = w - la;
            gb[j] = w - lb;
        }
        ra = rcarry_a; rb = rcarry_b;
        #pragma unroll
        for (int j = 7; j >= 0; --j) {
            float w = wbase + (float)j;
            if (m[j]) ra = w; else rb = w;
            ga[j] = fminf(ga[j], ra - w);
            gb[j] = fminf(gb[j], rb - w);
        }

        unsigned int pk[8];
        #pragma unroll
        for (int j = 0; j < 8; ++j) {
            unsigned int ua = (unsigned int)fminf(ga[j], 65535.0f);  // dist to 1
            unsigned int ub = (unsigned int)fminf(gb[j], 65535.0f);  // dist to 0
            pk[j] = ua | (ub << 16);
        }
        *reinterpret_cast<uint4*>(&gf[s][lane * 8])     = make_uint4(pk[0], pk[1], pk[2], pk[3]);
        *reinterpret_cast<uint4*>(&gf[s][lane * 8 + 4]) = make_uint4(pk[4], pk[5], pk[6], pk[7]);
    }
    __syncthreads();

    // ---------------- Phase B: window search + loss (2 rows/wave) ----------
    float acc_pd = 0.0f, acc_p = 0.0f, acc_t = 0.0f, acc_pt = 0.0f;
    const int c0 = lane * 4;          // group A cols; group B at +256

    #pragma unroll
    for (int half = 0; half < 2; ++half) {
        const int i  = r0 + wv + half * 8;    // pixel row (image-local)
        const int ci = wv + half * 8 + HALO;  // its LDS row
        const size_t rowoff = (size_t)b * H * W + (size_t)i * W;

        const float4 lgA = *reinterpret_cast<const float4*>(logits + rowoff + c0);
        const float4 lgB = *reinterpret_cast<const float4*>(logits + rowoff + c0 + 256);
        const uint4  vA  = *reinterpret_cast<const uint4*>(&gf[ci][c0]);
        const uint4  vB  = *reinterpret_cast<const uint4*>(&gf[ci][c0 + 256]);

        const unsigned int va[8] = { vA.x, vA.y, vA.z, vA.w, vB.x, vB.y, vB.z, vB.w };
        const float xv[8] = { lgA.x, lgA.y, lgA.z, lgA.w, lgB.x, lgB.y, lgB.z, lgB.w };

        unsigned int best[8], shf[8];
        #pragma unroll
        for (int k = 0; k < 8; ++k) {
            bool t = ((va[k] & 0xffffu) == 0u);     // g1==0 <=> target==1
            shf[k] = t ? 16u : 0u;                  // opposite-field shift
            unsigned int g = (va[k] >> shf[k]) & 0xffffu;
            best[k] = g * g;
        }

        #pragma unroll
        for (int r = 1; r <= 3; ++r) {
            const unsigned int rr = (unsigned int)(r * r);
            const uint4 uA = *reinterpret_cast<const uint4*>(&gf[ci - r][c0]);
            const uint4 uB = *reinterpret_cast<const uint4*>(&gf[ci - r][c0 + 256]);
            const uint4 dA = *reinterpret_cast<const uint4*>(&gf[ci + r][c0]);
            const uint4 dB = *reinterpret_cast<const uint4*>(&gf[ci + r][c0 + 256]);
            const unsigned int au[8] = { uA.x, uA.y, uA.z, uA.w, uB.x, uB.y, uB.z, uB.w };
            const unsigned int ad[8] = { dA.x, dA.y, dA.z, dA.w, dB.x, dB.y, dB.z, dB.w };
            #pragma unroll
            for (int k = 0; k < 8; ++k) {
                unsigned int gu = (au[k] >> shf[k]) & 0xffffu;
                unsigned int gd = (ad[k] >> shf[k]) & 0xffffu;
                best[k] = min(best[k], gu * gu + rr);   // v_mad_u32_u24
                best[k] = min(best[k], gd * gd + rr);
            }
        }

        // exact tail fallback (P ~ 2^-40 per pixel)
        #pragma unroll
        for (int k = 0; k < 8; ++k) {
            float bf = (float)best[k];
            if (bf > 16.0f) {
                const int col = (k < 4) ? (c0 + k) : (c0 + 256 + k - 4);
                const bool oppOne = (shf[k] == 0u);    // opposite class is 1
                for (int r = HALO + 1; r < H; ++r) {
                    const float rr = (float)(r * r);
                    if (rr >= bf) break;
                    const int ju = i - r, jd = i + r;
                    if (ju >= 0) {
                        float g = (float)row_nearest(timg + (size_t)ju * W, col, oppOne);
                        bf = fminf(bf, fmaf(g, g, rr));
                    }
                    if (jd < H) {
                        float g = (float)row_nearest(timg + (size_t)jd * W, col, oppOne);
                        bf = fminf(bf, fmaf(g, g, rr));
                    }
                }
            }
            const float dist = sqrtf(bf);               // own-class term is 0
            const float p = 1.0f / (1.0f + __expf(-xv[k]));
            const float tfv = shf[k] ? 1.0f : 0.0f;
            acc_pd += p * dist;
            acc_p  += p;
            acc_t  += tfv;
            acc_pt = fmaf(tfv, p, acc_pt);
        }
    }

    const float w_pd = wave_reduce_f(acc_pd);
    const float w_p  = wave_reduce_f(acc_p);
    const float w_t  = wave_reduce_f(acc_t);
    const float w_pt = wave_reduce_f(acc_pt);

    if (lane == 0) {
        sh[wv][0] = (double)w_pd; sh[wv][1] = (double)w_p;
        sh[wv][2] = (double)w_t;  sh[wv][3] = (double)w_pt;
    }
    __syncthreads();
    if (threadIdx.x == 0) {
        double s0 = 0.0, s1 = 0.0, s2 = 0.0, s3 = 0.0;
        #pragma unroll
        for (int q = 0; q < 8; ++q) {
            s0 += sh[q][0]; s1 += sh[q][1]; s2 += sh[q][2]; s3 += sh[q][3];
        }
        double* outp = partials + (size_t)blockIdx.x * 4;
        outp[0] = s0; outp[1] = s1; outp[2] = s2; outp[3] = s3;
    }
}

// ---------------------------------------------------------------------------
// Finalize: reduce NBLK partial quads, compute scalar loss.
// ---------------------------------------------------------------------------
__global__ void finalize_kernel(const double* __restrict__ partials,
                                float* __restrict__ out) {
    double a0 = 0.0, a1 = 0.0, a2 = 0.0, a3 = 0.0;
    for (int j = threadIdx.x; j < NBLK; j += 256) {
        const double* p = partials + (size_t)j * 4;
        a0 += p[0]; a1 += p[1]; a2 += p[2]; a3 += p[3];
    }
    a0 = wave_reduce_d(a0);
    a1 = wave_reduce_d(a1);
    a2 = wave_reduce_d(a2);
    a3 = wave_reduce_d(a3);

    __shared__ double sh[4][4];
    const int wid = threadIdx.x >> 6, lane = threadIdx.x & 63;
    if (lane == 0) {
        sh[wid][0] = a0; sh[wid][1] = a1; sh[wid][2] = a2; sh[wid][3] = a3;
    }
    __syncthreads();
    if (threadIdx.x == 0) {
        double sum_pd = sh[0][0] + sh[1][0] + sh[2][0] + sh[3][0];
        double sum_p  = sh[0][1] + sh[1][1] + sh[2][1] + sh[3][1];
        double sum_t  = sh[0][2] + sh[1][2] + sh[2][2] + sh[3][2];
        double sum_pt = sh[0][3] + sh[1][3] + sh[2][3] + sh[3][3];

        double mean_pd = sum_pd / (double)NPIX;
        double loss_b = BETA_C * mean_pd;
        double dice = (2.0 * sum_pt + SMOOTH_C) / (sum_p + sum_t + SMOOTH_C);
        double loss_d = 1.0 - dice;
        out[0] = (float)(ALPHA_C * loss_d + BETA_C * loss_b);
    }
}

// ---------------------------------------------------------------------------
extern "C" void kernel_launch(void* const* d_in, const int* in_sizes, int n_in,
                              void* d_out, int out_size, void* d_ws, size_t ws_size,
                              hipStream_t stream) {
    const float* logits = (const float*)d_in[0];   // [16,1,512,512] f32
    const int* tgt      = (const int*)d_in[1];     // [16,1,512,512] i32 (0/1)
    float* out = (float*)d_out;                    // scalar

    // Workspace: double partials[NBLK][4] (16 KB)
    double* partials = (double*)d_ws;

    edt_fused_kernel<<<NBLK, TPB, 0, stream>>>(logits, tgt, partials);
    finalize_kernel<<<1, 256, 0, stream>>>(partials, out);
}

// Round 8
// 21.895 us; speedup vs baseline: 12.2908x; 1.0208x over previous
//
#include <hip/hip_runtime.h>
#include <math.h>

// Problem constants (match reference setup_inputs)
constexpr int B = 16, H = 512, W = 512;
constexpr int NPIX = B * H * W;          // 4,194,304
constexpr int ROWS = 16;                 // pixel rows per block
constexpr int HALO = 2;                  // in-LDS window radius (tail is exact)
constexpr int LROWS = ROWS + 2 * HALO;   // 20 LDS rows -> 40 KB -> 4 blocks/CU
constexpr int TPB = 512;                 // 8 waves per block
constexpr int NBLK = B * (H / ROWS);     // 512 blocks

#define ALPHA_C 0.5
#define BETA_C 0.5
#define SMOOTH_C 1e-06
#define BIGV 1000000.0f

__device__ inline float wave_reduce_f(float v) {
    #pragma unroll
    for (int off = 32; off > 0; off >>= 1)
        v += __shfl_down(v, off, 64);
    return v;
}

__device__ inline double wave_reduce_d(double v) {
    #pragma unroll
    for (int off = 32; off > 0; off >>= 1)
        v += __shfl_down(v, off, 64);
    return v;
}

// Exact nearest-opposite-class distance within one row, scanning outward
// from column c. Used only by the (astronomically rare) tail path.
__device__ int row_nearest(const int* __restrict__ rowp, int c, bool oppOne) {
    for (int d = 0; d < W; ++d) {
        int l = c - d, r = c + d;
        if (l >= 0 && ((rowp[l] > 0) == oppOne)) return d;
        if (r <  W && ((rowp[r] > 0) == oppOne)) return d;
    }
    return 65535;
}

// ---------------------------------------------------------------------------
// Fused kernel. Each block owns a 16-row strip of one image.
// Prefetch: logits float4 pairs are loaded BEFORE Phase A so HBM latency
//   hides under the row scans (T14 async-split).
// Phase A: 8 waves compute exact 1D row distances (wave-parallel max/min
//   scans, bitwise-identical to the reference recurrence) for rows
//   r0-2 .. r0+17, packed u16x2 into LDS. Out-of-image rows get the
//   0xFFFFFFFF sentinel (g=65535; g^2+rr < 2^32, can never win).
// Phase B: each wave handles 2 pixel rows; each lane owns cols [lane*4,+4)
//   and [+256,+4) (16B/lane -> conflict-free LDS b128, coalesced float4).
//   Window candidates in u32 (mad+min_u32) — identical to the reference's
//   exact-integer f32 mins. Tail (best>9, P~3e-8/px) recomputes far rows
//   from tgt on demand — exact. Own-class EDT term is 0 (class = g1==0).
// Per-block f64 partials; finalize kernel reduces 512 quads.
// ---------------------------------------------------------------------------
__global__ void __launch_bounds__(TPB, 8)
edt_fused_kernel(const float* __restrict__ logits,
                 const int* __restrict__ tgt,
                 double* __restrict__ partials) {
    __shared__ __align__(16) unsigned int gf[LROWS][W];   // 40 KB
    __shared__ double sh[8][4];

    const int lane = threadIdx.x & 63;
    const int wv   = threadIdx.x >> 6;          // 0..7
    const int b    = blockIdx.x >> 5;           // image index (32 strips/image)
    const int r0   = (blockIdx.x & 31) * ROWS;  // first pixel row (image-local)
    const int* timg = tgt + (size_t)b * H * W;
    const int c0 = lane * 4;                    // group A cols; group B at +256

    // ---- logits prefetch for both Phase-B rows (hides under Phase A) ----
    float4 plg[2][2];
    #pragma unroll
    for (int half = 0; half < 2; ++half) {
        const size_t rowoff = (size_t)b * H * W + (size_t)(r0 + wv + half * 8) * W;
        plg[half][0] = *reinterpret_cast<const float4*>(logits + rowoff + c0);
        plg[half][1] = *reinterpret_cast<const float4*>(logits + rowoff + c0 + 256);
    }

    const float NEG = -(BIGV + 1.0f);
    const float POS = (float)W + BIGV;
    const float wbase = (float)(lane * 8);

    // ---------------- Phase A: row scans into LDS ----------------
    for (int s = wv; s < LROWS; s += 8) {
        const int grow = r0 - HALO + s;
        if (grow < 0 || grow >= H) {
            const uint4 sent = make_uint4(~0u, ~0u, ~0u, ~0u);
            *reinterpret_cast<uint4*>(&gf[s][lane * 8])     = sent;
            *reinterpret_cast<uint4*>(&gf[s][lane * 8 + 4]) = sent;
            continue;
        }
        const int* rowp = timg + (size_t)grow * W;
        const int4 t0 = *reinterpret_cast<const int4*>(rowp + lane * 8);
        const int4 t1 = *reinterpret_cast<const int4*>(rowp + lane * 8 + 4);
        bool m[8] = { t0.x > 0, t0.y > 0, t0.z > 0, t0.w > 0,
                      t1.x > 0, t1.y > 0, t1.z > 0, t1.w > 0 };

        // lane-local last/first hit indices
        float la = NEG, lb = NEG, ra = POS, rb = POS;
        #pragma unroll
        for (int j = 0; j < 8; ++j) {
            float w = wbase + (float)j;
            if (m[j]) la = w; else lb = w;
        }
        #pragma unroll
        for (int j = 7; j >= 0; --j) {
            float w = wbase + (float)j;
            if (m[j]) ra = w; else rb = w;
        }

        // wave inclusive max-scan (prefix)
        float sa = la, sb = lb;
        #pragma unroll
        for (int off = 1; off < 64; off <<= 1) {
            float ua = __shfl_up(sa, off, 64);
            float ub = __shfl_up(sb, off, 64);
            if (lane >= off) { sa = fmaxf(sa, ua); sb = fmaxf(sb, ub); }
        }
        float carry_a = __shfl_up(sa, 1, 64); if (lane == 0) carry_a = NEG;
        float carry_b = __shfl_up(sb, 1, 64); if (lane == 0) carry_b = NEG;

        // wave inclusive min-scan (suffix)
        float ta = ra, tb = rb;
        #pragma unroll
        for (int off = 1; off < 64; off <<= 1) {
            float ua = __shfl_down(ta, off, 64);
            float ub = __shfl_down(tb, off, 64);
            if (lane < 64 - off) { ta = fminf(ta, ua); tb = fminf(tb, ub); }
        }
        float rcarry_a = __shfl_down(ta, 1, 64); if (lane == 63) rcarry_a = POS;
        float rcarry_b = __shfl_down(tb, 1, 64); if (lane == 63) rcarry_b = POS;

        // per-element distances
        float ga[8], gb[8];
        la = carry_a; lb = carry_b;
        #pragma unroll
        for (int j = 0; j < 8; ++j) {
            float w = wbase + (float)j;
            if (m[j]) la = w; else lb = w;
            ga[j] = w - la;
            gb[j] = w - lb;
        }
        ra = rcarry_a; rb = rcarry_b;
        #pragma unroll
        for (int j = 7; j >= 0; --j) {
            float w = wbase + (float)j;
            if (m[j]) ra = w; else rb = w;
            ga[j] = fminf(ga[j], ra - w);
            gb[j] = fminf(gb[j], rb - w);
        }

        unsigned int pk[8];
        #pragma unroll
        for (int j = 0; j < 8; ++j) {
            unsigned int ua = (unsigned int)fminf(ga[j], 65535.0f);  // dist to 1
            unsigned int ub = (unsigned int)fminf(gb[j], 65535.0f);  // dist to 0
            pk[j] = ua | (ub << 16);
        }
        *reinterpret_cast<uint4*>(&gf[s][lane * 8])     = make_uint4(pk[0], pk[1], pk[2], pk[3]);
        *reinterpret_cast<uint4*>(&gf[s][lane * 8 + 4]) = make_uint4(pk[4], pk[5], pk[6], pk[7]);
    }
    __syncthreads();

    // ---------------- Phase B: window search + loss (2 rows/wave) ----------
    float acc_pd = 0.0f, acc_p = 0.0f, acc_t = 0.0f, acc_pt = 0.0f;

    #pragma unroll
    for (int half = 0; half < 2; ++half) {
        const int i  = r0 + wv + half * 8;    // pixel row (image-local)
        const int ci = wv + half * 8 + HALO;  // its LDS row

        const float4 lgA = plg[half][0];
        const float4 lgB = plg[half][1];
        const uint4  vA  = *reinterpret_cast<const uint4*>(&gf[ci][c0]);
        const uint4  vB  = *reinterpret_cast<const uint4*>(&gf[ci][c0 + 256]);

        const unsigned int va[8] = { vA.x, vA.y, vA.z, vA.w, vB.x, vB.y, vB.z, vB.w };
        const float xv[8] = { lgA.x, lgA.y, lgA.z, lgA.w, lgB.x, lgB.y, lgB.z, lgB.w };

        unsigned int best[8], shf[8];
        #pragma unroll
        for (int k = 0; k < 8; ++k) {
            bool t = ((va[k] & 0xffffu) == 0u);     // g1==0 <=> target==1
            shf[k] = t ? 16u : 0u;                  // opposite-field shift
            unsigned int g = (va[k] >> shf[k]) & 0xffffu;
            best[k] = g * g;
        }

        #pragma unroll
        for (int r = 1; r <= HALO; ++r) {
            const unsigned int rr = (unsigned int)(r * r);
            const uint4 uA = *reinterpret_cast<const uint4*>(&gf[ci - r][c0]);
            const uint4 uB = *reinterpret_cast<const uint4*>(&gf[ci - r][c0 + 256]);
            const uint4 dA = *reinterpret_cast<const uint4*>(&gf[ci + r][c0]);
            const uint4 dB = *reinterpret_cast<const uint4*>(&gf[ci + r][c0 + 256]);
            const unsigned int au[8] = { uA.x, uA.y, uA.z, uA.w, uB.x, uB.y, uB.z, uB.w };
            const unsigned int ad[8] = { dA.x, dA.y, dA.z, dA.w, dB.x, dB.y, dB.z, dB.w };
            #pragma unroll
            for (int k = 0; k < 8; ++k) {
                unsigned int gu = (au[k] >> shf[k]) & 0xffffu;
                unsigned int gd = (ad[k] >> shf[k]) & 0xffffu;
                best[k] = min(best[k], gu * gu + rr);
                best[k] = min(best[k], gd * gd + rr);
            }
        }

        // exact tail fallback: for r>HALO a candidate is >= (HALO+1)^2, so it
        // can only matter if best > (HALO+1)^2. P ~ 3e-8 per pixel.
        #pragma unroll
        for (int k = 0; k < 8; ++k) {
            float bf = (float)best[k];
            if (bf > (float)((HALO + 1) * (HALO + 1))) {
                const int col = (k < 4) ? (c0 + k) : (c0 + 256 + k - 4);
                const bool oppOne = (shf[k] == 0u);    // opposite class is 1
                for (int r = HALO + 1; r < H; ++r) {
                    const float rr = (float)(r * r);
                    if (rr >= bf) break;
                    const int ju = i - r, jd = i + r;
                    if (ju >= 0) {
                        float g = (float)row_nearest(timg + (size_t)ju * W, col, oppOne);
                        bf = fminf(bf, fmaf(g, g, rr));
                    }
                    if (jd < H) {
                        float g = (float)row_nearest(timg + (size_t)jd * W, col, oppOne);
                        bf = fminf(bf, fmaf(g, g, rr));
                    }
                }
            }
            const float dist = sqrtf(bf);               // own-class term is 0
            const float p = 1.0f / (1.0f + __expf(-xv[k]));
            const float tfv = shf[k] ? 1.0f : 0.0f;
            acc_pd += p * dist;
            acc_p  += p;
            acc_t  += tfv;
            acc_pt = fmaf(tfv, p, acc_pt);
        }
    }

    const float w_pd = wave_reduce_f(acc_pd);
    const float w_p  = wave_reduce_f(acc_p);
    const float w_t  = wave_reduce_f(acc_t);
    const float w_pt = wave_reduce_f(acc_pt);

    if (lane == 0) {
        sh[wv][0] = (double)w_pd; sh[wv][1] = (double)w_p;
        sh[wv][2] = (double)w_t;  sh[wv][3] = (double)w_pt;
    }
    __syncthreads();
    if (threadIdx.x == 0) {
        double s0 = 0.0, s1 = 0.0, s2 = 0.0, s3 = 0.0;
        #pragma unroll
        for (int q = 0; q < 8; ++q) {
            s0 += sh[q][0]; s1 += sh[q][1]; s2 += sh[q][2]; s3 += sh[q][3];
        }
        double* outp = partials + (size_t)blockIdx.x * 4;
        outp[0] = s0; outp[1] = s1; outp[2] = s2; outp[3] = s3;
    }
}

// ---------------------------------------------------------------------------
// Finalize: reduce NBLK partial quads, compute scalar loss.
// ---------------------------------------------------------------------------
__global__ void finalize_kernel(const double* __restrict__ partials,
                                float* __restrict__ out) {
    double a0 = 0.0, a1 = 0.0, a2 = 0.0, a3 = 0.0;
    for (int j = threadIdx.x; j < NBLK; j += 256) {
        const double* p = partials + (size_t)j * 4;
        a0 += p[0]; a1 += p[1]; a2 += p[2]; a3 += p[3];
    }
    a0 = wave_reduce_d(a0);
    a1 = wave_reduce_d(a1);
    a2 = wave_reduce_d(a2);
    a3 = wave_reduce_d(a3);

    __shared__ double sh[4][4];
    const int wid = threadIdx.x >> 6, lane = threadIdx.x & 63;
    if (lane == 0) {
        sh[wid][0] = a0; sh[wid][1] = a1; sh[wid][2] = a2; sh[wid][3] = a3;
    }
    __syncthreads();
    if (threadIdx.x == 0) {
        double sum_pd = sh[0][0] + sh[1][0] + sh[2][0] + sh[3][0];
        double sum_p  = sh[0][1] + sh[1][1] + sh[2][1] + sh[3][1];
        double sum_t  = sh[0][2] + sh[1][2] + sh[2][2] + sh[3][2];
        double sum_pt = sh[0][3] + sh[1][3] + sh[2][3] + sh[3][3];

        double mean_pd = sum_pd / (double)NPIX;
        double loss_b = BETA_C * mean_pd;
        double dice = (2.0 * sum_pt + SMOOTH_C) / (sum_p + sum_t + SMOOTH_C);
        double loss_d = 1.0 - dice;
        out[0] = (float)(ALPHA_C * loss_d + BETA_C * loss_b);
    }
}

// ---------------------------------------------------------------------------
extern "C" void kernel_launch(void* const* d_in, const int* in_sizes, int n_in,
                              void* d_out, int out_size, void* d_ws, size_t ws_size,
                              hipStream_t stream) {
    const float* logits = (const float*)d_in[0];   // [16,1,512,512] f32
    const int* tgt      = (const int*)d_in[1];     // [16,1,512,512] i32 (0/1)
    float* out = (float*)d_out;                    // scalar

    // Workspace: double partials[NBLK][4] (16 KB)
    double* partials = (double*)d_ws;

    edt_fused_kernel<<<NBLK, TPB, 0, stream>>>(logits, tgt, partials);
    finalize_kernel<<<1, 256, 0, stream>>>(partials, out);
}